// Round 3
// baseline (270.044 us; speedup 1.0000x reference)
//
#include <hip/hip_runtime.h>
#include <hip/hip_bf16.h>

#define BATCH 32
#define LL 512
#define DD 768
#define EPSC 1e-5f

typedef __attribute__((ext_vector_type(8))) short bf16x8;
typedef __attribute__((ext_vector_type(4))) float f32x4;

// ---------------------------------------------------------------------------
// Kernel 1: per-row scale s[b*L+l] = (eps + sum_d x^2)^(1/4)
// One wave per row (768 = 64 lanes * 3 float4).
// ---------------------------------------------------------------------------
__global__ __launch_bounds__(256) void k_scales(const float* __restrict__ x,
                                                float* __restrict__ s) {
    int wave = threadIdx.x >> 6;
    int lane = threadIdx.x & 63;
    int row = blockIdx.x * 4 + wave;                 // [0, 16384)
    const float4* xr = (const float4*)(x + (size_t)row * DD);
    float sum = 0.f;
#pragma unroll
    for (int i = 0; i < 3; i++) {
        float4 v = xr[lane + i * 64];
        sum += v.x * v.x + v.y * v.y + v.z * v.z + v.w * v.w;
    }
#pragma unroll
    for (int off = 32; off > 0; off >>= 1)
        sum += __shfl_xor(sum, off, 64);
    if (lane == 0) s[row] = sqrtf(sqrtf(EPSC + sum));
}

// ---------------------------------------------------------------------------
// Kernel 2: Yt[b][d][l] = bf16( s[b][l] * x[b][l][d] )   (transpose via LDS)
// 64x64 tile, row stride 65 floats -> both phases bank-conflict-free.
// ---------------------------------------------------------------------------
__global__ __launch_bounds__(256) void k_transpose(const float* __restrict__ x,
                                                   const float* __restrict__ s,
                                                   ushort* __restrict__ yt) {
    __shared__ float tile[64][65];
    __shared__ float svec[64];
    int b = blockIdx.z;
    int l0 = blockIdx.y * 64;
    int d0 = blockIdx.x * 64;
    int t = threadIdx.x;
    if (t < 64) svec[t] = s[b * LL + l0 + t];
    const float* xp = x + ((size_t)b * LL + l0) * DD + d0;
    int f = t & 15, lr0 = t >> 4;                     // f: float4 col, lr0: row
#pragma unroll
    for (int r = 0; r < 4; r++) {
        int l = lr0 + r * 16;
        float4 v = *(const float4*)(xp + (size_t)l * DD + f * 4);
#pragma unroll
        for (int j = 0; j < 4; j++)
            tile[l][f * 4 + j] = ((const float*)&v)[j];
    }
    __syncthreads();
    ushort* yp = yt + ((size_t)b * DD + d0) * LL + l0;
    int lc = t & 7, dl0 = t >> 3;                     // lc: l-chunk, dl0: d row
#pragma unroll
    for (int it = 0; it < 2; it++) {
        int d = dl0 + it * 32;
        bf16x8 w;
#pragma unroll
        for (int j = 0; j < 8; j++) {
            int l = lc * 8 + j;
            float v = tile[l][d] * svec[l];
            __hip_bfloat16 h = __float2bfloat16(v);
            w[j] = *(short*)&h;
        }
        *(bf16x8*)(yp + (size_t)d * LL + lc * 8) = w;
    }
}

// ---------------------------------------------------------------------------
// Kernel 3: C[b] = Yt[b]*Yt[b]^T, symmetric. 64x64 tile per BLOCK, 4 waves
// K-SPLIT (wave w does K in [w*128, w*128+128)). Fragments read directly
// from global (Yt L2-resident). No per-K-step barriers; only a 2-phase LDS
// tree reduction at the end. 9984 waves (39/CU demand) vs 2496 before --
// attacks the measured 13.8% occupancy / 6.3% MfmaUtil latency-bound state.
// ---------------------------------------------------------------------------
__global__ __launch_bounds__(256) void k_gemm(const ushort* __restrict__ yt,
                                              float* __restrict__ out) {
    __shared__ f32x4 red[2][16][64];                  // 32 KB exchange buffers
    int i = blockIdx.x;                               // [0, 2496)
    int xcd = i & 7, slot = i >> 3;                   // XCD round-robin
    int b = xcd + 8 * (slot / 78);
    int p = slot % 78;
    int t = p, tm = 0, rem = 12;
    while (t >= rem) { t -= rem; rem--; tm++; }
    int tn = tm + t;                                  // tm <= tn
    bool diag = (tm == tn);
    int m0 = tm * 64, n0 = tn * 64;
    int tid = threadIdx.x;
    int wv = tid >> 6, lane = tid & 63;
    int fr = lane & 15, ks4 = lane >> 4;              // frag row / k-slot
    const ushort* yb = yt + (size_t)b * DD * LL;
    const ushort* pa = yb + (size_t)(m0 + fr) * LL + ks4 * 8;
    const ushort* pb = yb + (size_t)(n0 + fr) * LL + ks4 * 8;
    if (diag) pb = pa;                                // diag: B = A

    f32x4 acc[4][4];
#pragma unroll
    for (int ii = 0; ii < 4; ii++)
#pragma unroll
        for (int j = 0; j < 4; j++) acc[ii][j] = (f32x4){0.f, 0.f, 0.f, 0.f};

    // K-split: wave wv covers 4 K-steps of 32, fully unrolled, no barriers.
#pragma unroll
    for (int ksl = 0; ksl < 4; ksl++) {
        int ko = (wv * 4 + ksl) * 32;
        bf16x8 af[4], bg[4];
#pragma unroll
        for (int ii = 0; ii < 4; ii++)
            af[ii] = *(const bf16x8*)(pa + (size_t)ii * 16 * LL + ko);
#pragma unroll
        for (int j = 0; j < 4; j++)
            bg[j] = *(const bf16x8*)(pb + (size_t)j * 16 * LL + ko);
#pragma unroll
        for (int ii = 0; ii < 4; ii++)
#pragma unroll
            for (int j = 0; j < 4; j++)
                acc[ii][j] = __builtin_amdgcn_mfma_f32_16x16x32_bf16(
                    af[ii], bg[j], acc[ii][j], 0, 0, 0);
    }

    // Reduction phase 1: waves 2,3 donate everything to waves 0,1.
    if (wv >= 2) {
#pragma unroll
        for (int ii = 0; ii < 4; ii++)
#pragma unroll
            for (int j = 0; j < 4; j++)
                red[wv - 2][ii * 4 + j][lane] = acc[ii][j];
    }
    __syncthreads();
    if (wv < 2) {
#pragma unroll
        for (int ii = 0; ii < 4; ii++)
#pragma unroll
            for (int j = 0; j < 4; j++)
                acc[ii][j] += red[wv][ii * 4 + j][lane];
    }
    __syncthreads();
    // Phase 2: w0 gives upper half (ii=2,3) to w1, w1 gives lower to w0.
    if (wv < 2) {
        int base = (wv == 0) ? 2 : 0;                 // half being given away
#pragma unroll
        for (int i2 = 0; i2 < 2; i2++)
#pragma unroll
            for (int j = 0; j < 4; j++)
                red[wv][i2 * 4 + j][lane] = acc[base + i2][j];
    }
    __syncthreads();
    if (wv >= 2) return;
    int iiLo = (wv == 0) ? 0 : 2;                     // half this wave keeps
#pragma unroll
    for (int i2 = 0; i2 < 2; i2++)
#pragma unroll
        for (int j = 0; j < 4; j++)
            acc[iiLo + i2][j] += red[wv ^ 1][i2 * 4 + j][lane];

    // Epilogue (waves 0,1 split the tile halves). C/D layout:
    // col = lane&15, row = (lane>>4)*4 + r. Mirror write float4; direct scalar.
    float* op = out + (size_t)b * DD * DD;
#pragma unroll
    for (int i2 = 0; i2 < 2; i2++) {
        int ii = iiLo + i2;
        int colb = m0 + ii * 16 + ks4 * 4;
#pragma unroll
        for (int j = 0; j < 4; j++) {
            int row = n0 + j * 16 + fr;
            f32x4 a = acc[ii][j];
            float4 v = {a[0], a[1], a[2], a[3]};
            *(float4*)(op + (size_t)row * DD + colb) = v;   // mirror (or diag)
        }
    }
    if (!diag) {
#pragma unroll
        for (int i2 = 0; i2 < 2; i2++) {
            int ii = iiLo + i2;
            int mbase = m0 + ii * 16 + ks4 * 4;
#pragma unroll
            for (int j = 0; j < 4; j++) {
                int n = n0 + j * 16 + fr;
#pragma unroll
                for (int r = 0; r < 4; r++)
                    op[(size_t)(mbase + r) * DD + n] = acc[ii][j][r];
            }
        }
    }
}

// ---------------------------------------------------------------------------
extern "C" void kernel_launch(void* const* d_in, const int* in_sizes, int n_in,
                              void* d_out, int out_size, void* d_ws, size_t ws_size,
                              hipStream_t stream) {
    const float* x = (const float*)d_in[0];
    float* s = (float*)d_ws;                                        // 64 KB
    ushort* yt = (ushort*)((char*)d_ws + 65536);                    // 25.2 MB bf16

    k_scales<<<dim3((BATCH * LL) / 4), 256, 0, stream>>>(x, s);
    k_transpose<<<dim3(DD / 64, LL / 64, BATCH), 256, 0, stream>>>(x, s, yt);
    k_gemm<<<dim3(78 * BATCH), 256, 0, stream>>>(yt, (float*)d_out);
}

// Round 4
// 155.744 us; speedup vs baseline: 1.7339x; 1.7339x over previous
//
#include <hip/hip_runtime.h>
#include <hip/hip_bf16.h>

#define BATCH 32
#define LL 512
#define DD 768
#define EPSC 1e-5f

typedef __attribute__((ext_vector_type(8))) short bf16x8;
typedef __attribute__((ext_vector_type(4))) float f32x4;

// ---------------------------------------------------------------------------
// Kernel 1: per-row scale s[b*L+l] = (eps + sum_d x^2)^(1/4)
// One wave per row (768 = 64 lanes * 3 float4).
// ---------------------------------------------------------------------------
__global__ __launch_bounds__(256) void k_scales(const float* __restrict__ x,
                                                float* __restrict__ s) {
    int wave = threadIdx.x >> 6;
    int lane = threadIdx.x & 63;
    int row = blockIdx.x * 4 + wave;                 // [0, 16384)
    const float4* xr = (const float4*)(x + (size_t)row * DD);
    float sum = 0.f;
#pragma unroll
    for (int i = 0; i < 3; i++) {
        float4 v = xr[lane + i * 64];
        sum += v.x * v.x + v.y * v.y + v.z * v.z + v.w * v.w;
    }
#pragma unroll
    for (int off = 32; off > 0; off >>= 1)
        sum += __shfl_xor(sum, off, 64);
    if (lane == 0) s[row] = sqrtf(sqrtf(EPSC + sum));
}

// ---------------------------------------------------------------------------
// Kernel 2: Yt[b][d][l] = bf16( s[b][l] * x[b][l][d] )   (transpose via LDS)
// 64x64 tile, row stride 65 floats -> both phases bank-conflict-free.
// ---------------------------------------------------------------------------
__global__ __launch_bounds__(256) void k_transpose(const float* __restrict__ x,
                                                   const float* __restrict__ s,
                                                   ushort* __restrict__ yt) {
    __shared__ float tile[64][65];
    __shared__ float svec[64];
    int b = blockIdx.z;
    int l0 = blockIdx.y * 64;
    int d0 = blockIdx.x * 64;
    int t = threadIdx.x;
    if (t < 64) svec[t] = s[b * LL + l0 + t];
    const float* xp = x + ((size_t)b * LL + l0) * DD + d0;
    int f = t & 15, lr0 = t >> 4;                     // f: float4 col, lr0: row
#pragma unroll
    for (int r = 0; r < 4; r++) {
        int l = lr0 + r * 16;
        float4 v = *(const float4*)(xp + (size_t)l * DD + f * 4);
#pragma unroll
        for (int j = 0; j < 4; j++)
            tile[l][f * 4 + j] = ((const float*)&v)[j];
    }
    __syncthreads();
    ushort* yp = yt + ((size_t)b * DD + d0) * LL + l0;
    int lc = t & 7, dl0 = t >> 3;                     // lc: l-chunk, dl0: d row
#pragma unroll
    for (int it = 0; it < 2; it++) {
        int d = dl0 + it * 32;
        bf16x8 w;
#pragma unroll
        for (int j = 0; j < 8; j++) {
            int l = lc * 8 + j;
            float v = tile[l][d] * svec[l];
            __hip_bfloat16 h = __float2bfloat16(v);
            w[j] = *(short*)&h;
        }
        *(bf16x8*)(yp + (size_t)d * LL + lc * 8) = w;
    }
}

// ---------------------------------------------------------------------------
// Epilogue helper: one 16-row block (ii) of the 64x64 tile. Values passed
// BY VALUE (no arrays, no refs) so acc can never be demoted to scratch
// (rule #20 -- Round 3's runtime-indexed acc spilled: 890 MB HBM writes).
// colb == mbase == m0 + ii*16 + ks4*4. Mirror write float4; direct scalar.
// ---------------------------------------------------------------------------
__device__ __forceinline__ void epi_row(float* __restrict__ op,
                                        f32x4 a0, f32x4 a1, f32x4 a2, f32x4 a3,
                                        int colb, int n0, int fr, bool diag) {
#define EPI_MIR(aj, j) do {                                          \
        int row_ = n0 + (j) * 16 + fr;                               \
        float4 v_ = {(aj)[0], (aj)[1], (aj)[2], (aj)[3]};            \
        *(float4*)(op + (size_t)row_ * DD + colb) = v_;              \
    } while (0)
    EPI_MIR(a0, 0); EPI_MIR(a1, 1); EPI_MIR(a2, 2); EPI_MIR(a3, 3);
    if (!diag) {
#define EPI_DIR(aj, j) do {                                          \
        int n_ = n0 + (j) * 16 + fr;                                 \
        _Pragma("unroll")                                            \
        for (int r = 0; r < 4; r++)                                  \
            op[(size_t)(colb + r) * DD + n_] = (aj)[r];              \
    } while (0)
        EPI_DIR(a0, 0); EPI_DIR(a1, 1); EPI_DIR(a2, 2); EPI_DIR(a3, 3);
#undef EPI_DIR
    }
#undef EPI_MIR
}

// ---------------------------------------------------------------------------
// Kernel 3: C[b] = Yt[b]*Yt[b]^T, symmetric. 64x64 tile per BLOCK, 4 waves
// K-SPLIT (wave w does K in [w*128, w*128+128)). Fragments read directly
// from global (Yt L2-resident: 786 KB/batch). No per-K-step barriers; only
// a 2-phase LDS tree reduction at the end. 9984 waves (39/CU demand).
// ALL acc indices are compile-time constant (explicit per-wave branches).
// ---------------------------------------------------------------------------
__global__ __launch_bounds__(256) void k_gemm(const ushort* __restrict__ yt,
                                              float* __restrict__ out) {
    __shared__ f32x4 red[2][16][64];                  // 32 KB exchange buffers
    int i = blockIdx.x;                               // [0, 2496)
    int xcd = i & 7, slot = i >> 3;                   // XCD round-robin
    int b = xcd + 8 * (slot / 78);
    int p = slot % 78;
    int t = p, tm = 0, rem = 12;
    while (t >= rem) { t -= rem; rem--; tm++; }
    int tn = tm + t;                                  // tm <= tn
    bool diag = (tm == tn);
    int m0 = tm * 64, n0 = tn * 64;
    int tid = threadIdx.x;
    int wv = tid >> 6, lane = tid & 63;
    int fr = lane & 15, ks4 = lane >> 4;              // frag row / k-slot
    const ushort* yb = yt + (size_t)b * DD * LL;
    const ushort* pa = yb + (size_t)(m0 + fr) * LL + ks4 * 8;
    const ushort* pb = yb + (size_t)(n0 + fr) * LL + ks4 * 8;
    if (diag) pb = pa;                                // diag: B = A

    f32x4 acc[4][4];
#pragma unroll
    for (int ii = 0; ii < 4; ii++)
#pragma unroll
        for (int j = 0; j < 4; j++) acc[ii][j] = (f32x4){0.f, 0.f, 0.f, 0.f};

    // K-split: wave wv covers 4 K-steps of 32, fully unrolled, no barriers.
    // wv only feeds ADDRESS arithmetic -- acc/af/bg indices all constant.
#pragma unroll
    for (int ksl = 0; ksl < 4; ksl++) {
        int ko = (wv * 4 + ksl) * 32;
        bf16x8 af[4], bg[4];
#pragma unroll
        for (int ii = 0; ii < 4; ii++)
            af[ii] = *(const bf16x8*)(pa + (size_t)ii * 16 * LL + ko);
#pragma unroll
        for (int j = 0; j < 4; j++)
            bg[j] = *(const bf16x8*)(pb + (size_t)j * 16 * LL + ko);
#pragma unroll
        for (int ii = 0; ii < 4; ii++)
#pragma unroll
            for (int j = 0; j < 4; j++)
                acc[ii][j] = __builtin_amdgcn_mfma_f32_16x16x32_bf16(
                    af[ii], bg[j], acc[ii][j], 0, 0, 0);
    }

    // Reduction phase 1: waves 2,3 donate everything to waves 0,1.
    // (red[wv-2] is LDS address arithmetic, not a register-array index.)
    if (wv >= 2) {
#pragma unroll
        for (int ii = 0; ii < 4; ii++)
#pragma unroll
            for (int j = 0; j < 4; j++)
                red[wv - 2][ii * 4 + j][lane] = acc[ii][j];
    }
    __syncthreads();
    if (wv < 2) {
#pragma unroll
        for (int ii = 0; ii < 4; ii++)
#pragma unroll
            for (int j = 0; j < 4; j++)
                acc[ii][j] += red[wv][ii * 4 + j][lane];
    }
    __syncthreads();
    // Phase 2 donate: wave0 gives rows ii=2,3; wave1 gives rows ii=0,1.
    // Explicit branches => constant acc indices.
    if (wv == 0) {
#pragma unroll
        for (int j = 0; j < 4; j++) {
            red[0][j][lane]     = acc[2][j];
            red[0][4 + j][lane] = acc[3][j];
        }
    } else if (wv == 1) {
#pragma unroll
        for (int j = 0; j < 4; j++) {
            red[1][j][lane]     = acc[0][j];
            red[1][4 + j][lane] = acc[1][j];
        }
    }
    __syncthreads();
    if (wv >= 2) return;

    float* op = out + (size_t)b * DD * DD;
    if (wv == 0) {                                    // keeps rows ii=0,1
#pragma unroll
        for (int j = 0; j < 4; j++) {
            acc[0][j] += red[1][j][lane];
            acc[1][j] += red[1][4 + j][lane];
        }
        epi_row(op, acc[0][0], acc[0][1], acc[0][2], acc[0][3],
                m0 + 0  + ks4 * 4, n0, fr, diag);
        epi_row(op, acc[1][0], acc[1][1], acc[1][2], acc[1][3],
                m0 + 16 + ks4 * 4, n0, fr, diag);
    } else {                                          // wave1 keeps ii=2,3
#pragma unroll
        for (int j = 0; j < 4; j++) {
            acc[2][j] += red[0][j][lane];
            acc[3][j] += red[0][4 + j][lane];
        }
        epi_row(op, acc[2][0], acc[2][1], acc[2][2], acc[2][3],
                m0 + 32 + ks4 * 4, n0, fr, diag);
        epi_row(op, acc[3][0], acc[3][1], acc[3][2], acc[3][3],
                m0 + 48 + ks4 * 4, n0, fr, diag);
    }
}

// ---------------------------------------------------------------------------
extern "C" void kernel_launch(void* const* d_in, const int* in_sizes, int n_in,
                              void* d_out, int out_size, void* d_ws, size_t ws_size,
                              hipStream_t stream) {
    const float* x = (const float*)d_in[0];
    float* s = (float*)d_ws;                                        // 64 KB
    ushort* yt = (ushort*)((char*)d_ws + 65536);                    // 25.2 MB bf16

    k_scales<<<dim3((BATCH * LL) / 4), 256, 0, stream>>>(x, s);
    k_transpose<<<dim3(DD / 64, LL / 64, BATCH), 256, 0, stream>>>(x, s, yt);
    k_gemm<<<dim3(78 * BATCH), 256, 0, stream>>>(yt, (float*)d_out);
}

// Round 5
// 137.756 us; speedup vs baseline: 1.9603x; 1.1306x over previous
//
#include <hip/hip_runtime.h>
#include <hip/hip_bf16.h>

#define BATCH 32
#define LL 512
#define DD 768
#define EPSC 1e-5f

typedef __attribute__((ext_vector_type(8))) short bf16x8;
typedef __attribute__((ext_vector_type(4))) float f32x4;

// ---------------------------------------------------------------------------
// Kernel 1: per-row scale s[b*L+l] = (eps + sum_d x^2)^(1/4)
// One wave per row (768 = 64 lanes * 3 float4).
// ---------------------------------------------------------------------------
__global__ __launch_bounds__(256) void k_scales(const float* __restrict__ x,
                                                float* __restrict__ s) {
    int wave = threadIdx.x >> 6;
    int lane = threadIdx.x & 63;
    int row = blockIdx.x * 4 + wave;                 // [0, 16384)
    const float4* xr = (const float4*)(x + (size_t)row * DD);
    float sum = 0.f;
#pragma unroll
    for (int i = 0; i < 3; i++) {
        float4 v = xr[lane + i * 64];
        sum += v.x * v.x + v.y * v.y + v.z * v.z + v.w * v.w;
    }
#pragma unroll
    for (int off = 32; off > 0; off >>= 1)
        sum += __shfl_xor(sum, off, 64);
    if (lane == 0) s[row] = sqrtf(sqrtf(EPSC + sum));
}

// ---------------------------------------------------------------------------
// Kernel 2: Yt[b][d][l] = bf16( s[b][l] * x[b][l][d] )   (transpose via LDS)
// 64x64 tile, row stride 65 floats -> both phases bank-conflict-free.
// ---------------------------------------------------------------------------
__global__ __launch_bounds__(256) void k_transpose(const float* __restrict__ x,
                                                   const float* __restrict__ s,
                                                   ushort* __restrict__ yt) {
    __shared__ float tile[64][65];
    __shared__ float svec[64];
    int b = blockIdx.z;
    int l0 = blockIdx.y * 64;
    int d0 = blockIdx.x * 64;
    int t = threadIdx.x;
    if (t < 64) svec[t] = s[b * LL + l0 + t];
    const float* xp = x + ((size_t)b * LL + l0) * DD + d0;
    int f = t & 15, lr0 = t >> 4;                     // f: float4 col, lr0: row
#pragma unroll
    for (int r = 0; r < 4; r++) {
        int l = lr0 + r * 16;
        float4 v = *(const float4*)(xp + (size_t)l * DD + f * 4);
#pragma unroll
        for (int j = 0; j < 4; j++)
            tile[l][f * 4 + j] = ((const float*)&v)[j];
    }
    __syncthreads();
    ushort* yp = yt + ((size_t)b * DD + d0) * LL + l0;
    int lc = t & 7, dl0 = t >> 3;                     // lc: l-chunk, dl0: d row
#pragma unroll
    for (int it = 0; it < 2; it++) {
        int d = dl0 + it * 32;
        bf16x8 w;
#pragma unroll
        for (int j = 0; j < 8; j++) {
            int l = lc * 8 + j;
            float v = tile[l][d] * svec[l];
            __hip_bfloat16 h = __float2bfloat16(v);
            w[j] = *(short*)&h;
        }
        *(bf16x8*)(yp + (size_t)d * LL + lc * 8) = w;
    }
}

// ---------------------------------------------------------------------------
// Kernel 3: C[b] = Yt[b]*Yt[b]^T, symmetric. Harness-proven staged structure
// (64x64 tile, 2x2 waves, gray-swizzled LDS, 0 bank conflicts) + the T3
// minimal 2-phase pipeline: DOUBLE-BUFFERED 8 KB tiles, STAGE(t+1) issued
// BEFORE compute(t), ONE __syncthreads per K-step (its vmcnt0+lgkm0 drain is
// the exact fence needed). 16 barriers instead of 32; stage latency hides
// under ds_read+MFMA and 8-blocks/CU TLP (16 KB LDS, ~92 VGPR).
// Safety of 1 barrier/step: iter t reads buf[t&1] (staged at t-1, drained by
// t-1's vmcnt0) and overwrites buf[(t+1)&1], whose readers finished before
// the t-1 barrier. No race window.
// ---------------------------------------------------------------------------
__global__ __launch_bounds__(256) void k_gemm(const ushort* __restrict__ yt,
                                              float* __restrict__ out) {
    __shared__ ushort At[2][64 * 32];                 // 2 x 4 KB, [m][k swz]
    __shared__ ushort Bt[2][64 * 32];
    int i = blockIdx.x;                               // [0, 2496)
    int xcd = i & 7, slot = i >> 3;                   // XCD round-robin
    int b = xcd + 8 * (slot / 78);
    int p = slot % 78;
    int t = p, tm = 0, rem = 12;
    while (t >= rem) { t -= rem; rem--; tm++; }
    int tn = tm + t;                                  // tm <= tn
    bool diag = (tm == tn);
    int m0 = tm * 64, n0 = tn * 64;
    int tid = threadIdx.x;
    int wave = tid >> 6, lane = tid & 63;
    int wr = wave >> 1, wc = wave & 1;                // 2x2 waves, 32x32 each
    const ushort* yb = yt + (size_t)b * DD * LL;

    f32x4 acc[2][2];
#pragma unroll
    for (int ii = 0; ii < 2; ii++)
#pragma unroll
        for (int j = 0; j < 2; j++) acc[ii][j] = (f32x4){0.f, 0.f, 0.f, 0.f};

    // staging: wave stages rows wave*16 + (lane>>2); chunk gray-swizzled
    int srow = lane >> 2;
    int ssw = (srow ^ (srow >> 1)) & 3;
    int scol = ((lane & 3) ^ ssw) * 8;
    int rloc = wave * 16 + srow;
    const ushort* gA = yb + (size_t)(m0 + rloc) * LL + scol;
    const ushort* gB = yb + (size_t)(n0 + rloc) * LL + scol;
    // frag read: logical chunk q=lane>>4 lives at slot q ^ gray(row&15)
    int fr = lane & 15;
    int fsw = (fr ^ (fr >> 1)) & 3;
    int fslot = (lane >> 4) ^ fsw;

#define STAGE(buf, ks) do {                                                   \
        int k0_ = (ks) * 32;                                                  \
        __builtin_amdgcn_global_load_lds(                                     \
            (const __attribute__((address_space(1))) void*)(gA + k0_),        \
            (__attribute__((address_space(3))) void*)(At[buf] + wave * 16 * 32), \
            16, 0, 0);                                                        \
        if (!diag)                                                            \
            __builtin_amdgcn_global_load_lds(                                 \
                (const __attribute__((address_space(1))) void*)(gB + k0_),    \
                (__attribute__((address_space(3))) void*)(Bt[buf] + wave * 16 * 32), \
                16, 0, 0);                                                    \
    } while (0)

    STAGE(0, 0);
    __syncthreads();                                  // buf0 ready
    for (int ks = 0; ks < 16; ks++) {
        int cur = ks & 1;
        if (ks < 15) STAGE(cur ^ 1, ks + 1);          // prefetch next tile
        const ushort* Ab = At[cur];
        const ushort* Bb = diag ? At[cur] : Bt[cur];
        bf16x8 afrag[2], bfrag[2];
#pragma unroll
        for (int ii = 0; ii < 2; ii++) {
            int m = wr * 32 + ii * 16 + fr;
            afrag[ii] = *(const bf16x8*)(Ab + m * 32 + fslot * 8);
            int n = wc * 32 + ii * 16 + fr;
            bfrag[ii] = *(const bf16x8*)(Bb + n * 32 + fslot * 8);
        }
#pragma unroll
        for (int ii = 0; ii < 2; ii++)
#pragma unroll
            for (int j = 0; j < 2; j++)
                acc[ii][j] = __builtin_amdgcn_mfma_f32_16x16x32_bf16(
                    afrag[ii], bfrag[j], acc[ii][j], 0, 0, 0);
        if (ks < 15) __syncthreads();                 // drain stage + handoff
    }
#undef STAGE

    // Epilogue. C/D layout: col = lane&15, row = (lane>>4)*4 + r.
    // Mirror (transposed) write is float4; direct write scalar (off-diag).
    float* op = out + (size_t)b * DD * DD;
#pragma unroll
    for (int ii = 0; ii < 2; ii++) {
        int colb = m0 + wr * 32 + ii * 16 + (lane >> 4) * 4;
#pragma unroll
        for (int j = 0; j < 2; j++) {
            int row = n0 + wc * 32 + j * 16 + fr;
            float4 v = {acc[ii][j][0], acc[ii][j][1], acc[ii][j][2], acc[ii][j][3]};
            *(float4*)(op + (size_t)row * DD + colb) = v;   // mirror (or diag)
        }
    }
    if (!diag) {
#pragma unroll
        for (int ii = 0; ii < 2; ii++) {
            int mbase = m0 + wr * 32 + ii * 16 + (lane >> 4) * 4;
#pragma unroll
            for (int j = 0; j < 2; j++) {
                int n = n0 + wc * 32 + j * 16 + fr;
#pragma unroll
                for (int r = 0; r < 4; r++)
                    op[(size_t)(mbase + r) * DD + n] = acc[ii][j][r];
            }
        }
    }
}

// ---------------------------------------------------------------------------
extern "C" void kernel_launch(void* const* d_in, const int* in_sizes, int n_in,
                              void* d_out, int out_size, void* d_ws, size_t ws_size,
                              hipStream_t stream) {
    const float* x = (const float*)d_in[0];
    float* s = (float*)d_ws;                                        // 64 KB
    ushort* yt = (ushort*)((char*)d_ws + 65536);                    // 25.2 MB bf16

    k_scales<<<dim3((BATCH * LL) / 4), 256, 0, stream>>>(x, s);
    k_transpose<<<dim3(DD / 64, LL / 64, BATCH), 256, 0, stream>>>(x, s, yt);
    k_gemm<<<dim3(78 * BATCH), 256, 0, stream>>>(yt, (float*)d_out);
}

// Round 7
// 130.810 us; speedup vs baseline: 2.0644x; 1.0531x over previous
//
#include <hip/hip_runtime.h>
#include <hip/hip_bf16.h>

#define BATCH 32
#define LL 512
#define DD 768
#define EPSC 1e-5f

typedef __attribute__((ext_vector_type(8))) short bf16x8;
typedef __attribute__((ext_vector_type(4))) float f32x4;

// ---------------------------------------------------------------------------
// Kernel 1 (fused prep): block = (l-block of 64 rows, batch). Phase 1 computes
// w[l] = (eps + sum_d x^2)^(1/4) in-register (4 lanes per row, 2 shfl).
// Phase 2 = the harness-verified 64x64 LDS transpose body, iterated over the
// 12 d-tiles (x re-reads come from L2: the block's 196 KB was just read).
// Saves a full 50 MB HBM pass vs separate k_scales + k_transpose.
// ---------------------------------------------------------------------------
__global__ __launch_bounds__(256) void k_prep(const float* __restrict__ x,
                                              ushort* __restrict__ yt) {
    __shared__ float tile[64][65];
    __shared__ float svec[64];
    int lb = blockIdx.x;                              // [0,8) l-block
    int b = blockIdx.y;
    int l0 = lb * 64;
    int t = threadIdx.x;

    // Phase 1: row r = t>>2 (0..63), quarter q = t&3 covers 192 floats.
    {
        int r = t >> 2, q = t & 3;
        const float4* xr = (const float4*)(x + ((size_t)b * LL + l0 + r) * DD) + q * 48;
        float sum = 0.f;
#pragma unroll 8
        for (int i = 0; i < 48; i++) {
            float4 v = xr[i];
            sum += v.x * v.x + v.y * v.y + v.z * v.z + v.w * v.w;
        }
        sum += __shfl_xor(sum, 1, 64);
        sum += __shfl_xor(sum, 2, 64);
        if (q == 0) svec[r] = sqrtf(sqrtf(EPSC + sum));
    }
    __syncthreads();

    // Phase 2: 12 x (load 64x64 tile -> transpose+scale -> bf16 store).
    const float* xb = x + ((size_t)b * LL + l0) * DD;
    int f = t & 15, lr0 = t >> 4;                     // f: float4 col, lr0: row
    int lc = t & 7, dl0 = t >> 3;                     // lc: l-chunk, dl0: d row
    for (int dt = 0; dt < 12; dt++) {
        int d0 = dt * 64;
#pragma unroll
        for (int r = 0; r < 4; r++) {
            int l = lr0 + r * 16;
            float4 v = *(const float4*)(xb + (size_t)l * DD + d0 + f * 4);
#pragma unroll
            for (int j = 0; j < 4; j++)
                tile[l][f * 4 + j] = ((const float*)&v)[j];
        }
        __syncthreads();
        ushort* yp = yt + ((size_t)b * DD + d0) * LL + l0;
#pragma unroll
        for (int it = 0; it < 2; it++) {
            int d = dl0 + it * 32;
            bf16x8 w;
#pragma unroll
            for (int j = 0; j < 8; j++) {
                int l = lc * 8 + j;
                float v = tile[l][d] * svec[l];
                __hip_bfloat16 h = __float2bfloat16(v);
                w[j] = *(short*)&h;
            }
            *(bf16x8*)(yp + (size_t)d * LL + lc * 8) = w;
        }
        __syncthreads();
    }
}

// ---------------------------------------------------------------------------
// Kernel 2: C[b] = Yt[b]*Yt[b]^T, symmetric. R5's verified single-barrier
// double-buffered structure with BK 32 -> 64: 8 K-steps (half the barriers),
// 8 MFMAs + 8 ds_read_b128 per wave per barrier (2x work to hide stage
// latency). LDS 32 KB (2x16 KB dbuf) -> 5 blocks/CU, 20 waves/CU, unchanged.
// Swizzle: row-major [64][8 chunks of 16B]; physical chunk c holds logical
// chunk c ^ (row&7). Staged via pre-swizzled GLOBAL addresses (linear LDS
// dest, required by global_load_lds); frag reads apply the same XOR
// (both-sides-or-neither, rule #21). Frag-read bank aliasing: 2-way (free).
// ---------------------------------------------------------------------------
__global__ __launch_bounds__(256) void k_gemm(const ushort* __restrict__ yt,
                                              float* __restrict__ out) {
    __shared__ ushort At[2][64 * 64];                 // 2 x 8 KB
    __shared__ ushort Bt[2][64 * 64];
    int i = blockIdx.x;                               // [0, 2496)
    int xcd = i & 7, slot = i >> 3;                   // XCD round-robin
    int b = xcd + 8 * (slot / 78);
    int p = slot % 78;
    int t = p, tm = 0, rem = 12;
    while (t >= rem) { t -= rem; rem--; tm++; }
    int tn = tm + t;                                  // tm <= tn
    bool diag = (tm == tn);
    int m0 = tm * 64, n0 = tn * 64;
    int tid = threadIdx.x;
    int wave = tid >> 6, lane = tid & 63;
    int wr = wave >> 1, wc = wave & 1;                // 2x2 waves, 32x32 each
    const ushort* yb = yt + (size_t)b * DD * LL;

    f32x4 acc[2][2];
#pragma unroll
    for (int ii = 0; ii < 2; ii++)
#pragma unroll
        for (int j = 0; j < 2; j++) acc[ii][j] = (f32x4){0.f, 0.f, 0.f, 0.f};

    // Staging geometry: issue i (0,1) covers physical 16B-slots s = i*256+tid;
    // row = s>>3, phys chunk = s&7, logical chunk = phys ^ (row&7).
    int s0 = tid, s1 = 256 + tid;
    int sr0 = s0 >> 3, sc0 = (s0 & 7) ^ (sr0 & 7);
    int sr1 = s1 >> 3, sc1 = (s1 & 7) ^ (sr1 & 7);
    const ushort* gA0 = yb + (size_t)(m0 + sr0) * LL + sc0 * 8;
    const ushort* gA1 = yb + (size_t)(m0 + sr1) * LL + sc1 * 8;
    const ushort* gB0 = yb + (size_t)(n0 + sr0) * LL + sc0 * 8;
    const ushort* gB1 = yb + (size_t)(n0 + sr1) * LL + sc1 * 8;
    int ldsOff0 = (0 * 256 + wave * 64) * 8;          // wave-uniform, +lane*16B
    int ldsOff1 = (1 * 256 + wave * 64) * 8;

    // Frag read: lane (fr, ks4); row mr chunk h*4+ks4 lives at slot ^(mr&7).
    int fr = lane & 15, ks4 = lane >> 4;

#define STAGE(buf, ks) do {                                                   \
        int k0_ = (ks) * 64;                                                  \
        __builtin_amdgcn_global_load_lds(                                     \
            (const __attribute__((address_space(1))) void*)(gA0 + k0_),       \
            (__attribute__((address_space(3))) void*)(At[buf] + ldsOff0),     \
            16, 0, 0);                                                        \
        __builtin_amdgcn_global_load_lds(                                     \
            (const __attribute__((address_space(1))) void*)(gA1 + k0_),       \
            (__attribute__((address_space(3))) void*)(At[buf] + ldsOff1),     \
            16, 0, 0);                                                        \
        if (!diag) {                                                          \
            __builtin_amdgcn_global_load_lds(                                 \
                (const __attribute__((address_space(1))) void*)(gB0 + k0_),   \
                (__attribute__((address_space(3))) void*)(Bt[buf] + ldsOff0), \
                16, 0, 0);                                                    \
            __builtin_amdgcn_global_load_lds(                                 \
                (const __attribute__((address_space(1))) void*)(gB1 + k0_),   \
                (__attribute__((address_space(3))) void*)(Bt[buf] + ldsOff1), \
                16, 0, 0);                                                    \
        }                                                                     \
    } while (0)

    STAGE(0, 0);
    __syncthreads();                                  // buf0 ready
    for (int ks = 0; ks < 8; ks++) {
        int cur = ks & 1;
        if (ks < 7) STAGE(cur ^ 1, ks + 1);           // prefetch next tile
        const ushort* Ab = At[cur];
        const ushort* Bb = diag ? At[cur] : Bt[cur];
        bf16x8 af[2][2], bf[2][2];
#pragma unroll
        for (int ii = 0; ii < 2; ii++) {
            int mr = wr * 32 + ii * 16 + fr;
            int nr = wc * 32 + ii * 16 + fr;
#pragma unroll
            for (int h = 0; h < 2; h++) {
                int slm = ((h * 4 + ks4) ^ (mr & 7)) * 8;
                int sln = ((h * 4 + ks4) ^ (nr & 7)) * 8;
                af[ii][h] = *(const bf16x8*)(Ab + mr * 64 + slm);
                bf[ii][h] = *(const bf16x8*)(Bb + nr * 64 + sln);
            }
        }
#pragma unroll
        for (int ii = 0; ii < 2; ii++)
#pragma unroll
            for (int j = 0; j < 2; j++)
#pragma unroll
                for (int h = 0; h < 2; h++)
                    acc[ii][j] = __builtin_amdgcn_mfma_f32_16x16x32_bf16(
                        af[ii][h], bf[j][h], acc[ii][j], 0, 0, 0);
        if (ks < 7) __syncthreads();                  // drain stage + handoff
    }
#undef STAGE

    // Epilogue. C/D layout: col = lane&15, row = (lane>>4)*4 + r.
    // Mirror (transposed) write is float4; direct write scalar (off-diag).
    float* op = out + (size_t)b * DD * DD;
#pragma unroll
    for (int ii = 0; ii < 2; ii++) {
        int colb = m0 + wr * 32 + ii * 16 + (lane >> 4) * 4;
#pragma unroll
        for (int j = 0; j < 2; j++) {
            int row = n0 + wc * 32 + j * 16 + fr;
            float4 v = {acc[ii][j][0], acc[ii][j][1], acc[ii][j][2], acc[ii][j][3]};
            *(float4*)(op + (size_t)row * DD + colb) = v;   // mirror (or diag)
        }
    }
    if (!diag) {
#pragma unroll
        for (int ii = 0; ii < 2; ii++) {
            int mbase = m0 + wr * 32 + ii * 16 + (lane >> 4) * 4;
#pragma unroll
            for (int j = 0; j < 2; j++) {
                int n = n0 + wc * 32 + j * 16 + fr;
#pragma unroll
                for (int r = 0; r < 4; r++)
                    op[(size_t)(mbase + r) * DD + n] = acc[ii][j][r];
            }
        }
    }
}

// ---------------------------------------------------------------------------
extern "C" void kernel_launch(void* const* d_in, const int* in_sizes, int n_in,
                              void* d_out, int out_size, void* d_ws, size_t ws_size,
                              hipStream_t stream) {
    const float* x = (const float*)d_in[0];
    ushort* yt = (ushort*)d_ws;                                     // 25.2 MB bf16

    k_prep<<<dim3(LL / 64, BATCH), 256, 0, stream>>>(x, yt);
    k_gemm<<<dim3(78 * BATCH), 256, 0, stream>>>(yt, (float*)d_out);
}